// Round 19
// baseline (266.178 us; speedup 1.0000x reference)
//
#include <hip/hip_runtime.h>
#include <hip/hip_bf16.h>

typedef __attribute__((ext_vector_type(8))) short short8;
typedef __attribute__((ext_vector_type(4))) short short4v;
typedef __attribute__((ext_vector_type(4))) float f32x4;

__device__ __forceinline__ short f2bf(float f) {
  __hip_bfloat16 h = __float2bfloat16(f);
  return *reinterpret_cast<short*>(&h);
}
__device__ __forceinline__ float bf2f(short s) {
  return __uint_as_float(((unsigned)(unsigned short)s) << 16);
}
__device__ __forceinline__ void glds16(const short* src, short* dst) {
  __builtin_amdgcn_global_load_lds(
      (const __attribute__((address_space(1))) unsigned int*)src,
      (__attribute__((address_space(3))) unsigned int*)dst, 16, 0, 0);
}
__device__ __forceinline__ float wave_red_sum(float v) {
  for (int i = 1; i < 64; i <<= 1) v += __shfl_xor(v, i);
  return v;
}

// ---- merged pre-phase A: cvt_w4 (blocks 0..1023) U gn_stats1 (1024..1279) ----
__global__ __launch_bounds__(256) void pre_a(const float* __restrict__ w0, short* __restrict__ o0,
                                             const float* __restrict__ w1, short* __restrict__ o1,
                                             const float* __restrict__ w2, short* __restrict__ o2,
                                             const float* __restrict__ w3, short* __restrict__ o3,
                                             const float* __restrict__ x, float* __restrict__ part) {
  int b = blockIdx.x;
  if (b < 1024) {
    int which = b >> 8;
    const float* w = (which == 0) ? w0 : (which == 1) ? w1 : (which == 2) ? w2 : w3;
    short* o       = (which == 0) ? o0 : (which == 1) ? o1 : (which == 2) ? o2 : o3;
    int i = (b & 255) * 256 + threadIdx.x;
    float4 v = ((const float4*)w)[i];
    short4v r;
    r.x = f2bf(v.x); r.y = f2bf(v.y); r.z = f2bf(v.z); r.w = f2bf(v.w);
    *(short4v*)&o[i*4] = r;
    return;
  }
  int u = b - 1024;
  int g = u & 31, s = u >> 5;
  const float4* base = (const float4*)(x + (size_t)g * 262144 + (size_t)s * 32768);
  float sum = 0.f, sq = 0.f;
  for (int i = threadIdx.x; i < 8192; i += 256) {
    float4 v = base[i];
    sum += v.x + v.y + v.z + v.w;
    sq  += v.x*v.x + v.y*v.y + v.z*v.z + v.w*v.w;
  }
  sum = wave_red_sum(sum); sq = wave_red_sum(sq);
  __shared__ float ls[4], lq[4];
  int w = threadIdx.x >> 6, lane = threadIdx.x & 63;
  if (lane == 0) { ls[w] = sum; lq[w] = sq; }
  __syncthreads();
  if (threadIdx.x == 0) {
    part[(g*8 + s)*2 + 0] = ls[0]+ls[1]+ls[2]+ls[3];
    part[(g*8 + s)*2 + 1] = lq[0]+lq[1]+lq[2]+lq[3];
  }
}

// ---- merged pre-phase B: t512 (0..63) U gn_stats2 (64) U bpv_k (65..66) ----
__global__ __launch_bounds__(256) void pre_b(const short* __restrict__ in, short* __restrict__ out,
                                             const float* __restrict__ part, float* __restrict__ stats,
                                             const float* __restrict__ wp, const float* __restrict__ bv,
                                             float* __restrict__ bpv) {
  __shared__ short T[64 * 72];
  int b = blockIdx.x;
  int tid = threadIdx.x;
  if (b < 64) {
    int c0 = (b & 7) * 64, i0 = (b >> 3) * 64;
#pragma unroll
    for (int it = 0; it < 2; ++it) {
      int u = it * 256 + tid;
      int r = u >> 3, k8 = (u & 7) * 8;
      *(short8*)&T[r * 72 + k8] = *(const short8*)&in[(size_t)(c0 + r) * 512 + i0 + k8];
    }
    __syncthreads();
#pragma unroll
    for (int it = 0; it < 2; ++it) {
      int u = it * 256 + tid;
      int c = u & 63, tg = u >> 6;
      short8 o;
#pragma unroll
      for (int j = 0; j < 8; ++j) o[j] = T[(tg * 8 + j) * 72 + c];
      *(short8*)&out[(size_t)(i0 + c) * 512 + c0 + tg * 8] = o;
    }
    return;
  }
  if (b == 64) {
    int g = tid;
    if (g < 32) {
      float s1 = 0.f, s2 = 0.f;
      for (int s = 0; s < 8; ++s) { s1 += part[(g*8+s)*2]; s2 += part[(g*8+s)*2+1]; }
      float mean = s1 * (1.f/262144.f);
      float var  = s2 * (1.f/262144.f) - mean*mean;
      stats[g]      = mean;
      stats[32 + g] = rsqrtf(var + 1e-6f);
    }
    return;
  }
  int o = (b - 65) * 256 + tid;
  float s = 0.f;
  for (int c = 0; c < 512; ++c) s += wp[(size_t)o * 512 + c] * bv[c];
  bpv[o] = s;
}

// ---- tiled GEMM, 3-buffer, single barrier per k-step (R12 core) ----
// G_S: 256x256 tile, 16 waves (1024 thr), 1 blk/CU — 1.5x fewer staged
// bytes/FLOP at equal waves/CU. Others: 128x256, 8 waves, 2 blk/CU.
// Riders: G_WPV blocks>=8 = gn_apply; G_PVT blocks>=512 = rowsum.
enum { G_QKVW = 0, G_S = 1, G_PVT = 2, G_WPV = 3 };

template<int MODE, int NKT>
__global__ __launch_bounds__(MODE == G_S ? 1024 : 512, MODE == G_S ? 1 : 4)
void gemm256(
    const short* __restrict__ A, const short* __restrict__ B0,
    const short* __restrict__ B1, const short* __restrict__ B2,
    short* __restrict__ out0, short* __restrict__ outT,
    const float* __restrict__ bias0, const float* __restrict__ bias1, const float* __restrict__ bias2,
    float* __restrict__ spart, float scale0,
    int lda, int ldb) {
  constexpr int THREADS = (MODE == G_S) ? 1024 : 512;
  constexpr int BM      = (MODE == G_S) ? 256 : 128;
  constexpr int AR32    = BM * 32;              // A region (shorts)
  constexpr int BUFSZ   = (BM + 256) * 32;      // per staging buffer (shorts)
  constexpr int LSSZ    = (MODE == G_S) ? 67584 : 36864;
  constexpr int NVM     = (MODE == G_S) ? 2 : 3;  // glds per stage

  const int tid  = threadIdx.x;
  const int d    = blockIdx.x;

  if (MODE == G_WPV && d >= 8) {
    // ---- gn_apply rider (2048 blocks, 512 thr; bit-identical math) ----
    int u = d - 8;
    int n  = (u & 7) * 512 + tid;
    int c0 = ((u >> 3) & 63) * 8;
    int t  = u >> 9;
    const float* xx = (const float*)B1;
    short8 o8;
#pragma unroll
    for (int j = 0; j < 8; ++j) {
      int c = c0 + j, g = c >> 4;
      float v  = xx[(size_t)c * 16384 + t * 4096 + n];
      float hv = (v - bias0[g]) * bias0[32 + g] * bias1[c] + bias2[c];
      o8[j] = f2bf(hv);
    }
    *(short8*)&outT[((size_t)t * 4096 + n) * 512 + c0] = o8;
    return;
  }
  if (MODE == G_PVT && d >= 512) {
    // ---- rowsum rider (32 blocks, 512 thr; rowsum_k's exact order) ----
    int row = (d - 512) * 512 + tid;
    const f32x4* p = (const f32x4*)(spart + (size_t)row * 32);
    float s = 0.f;
#pragma unroll
    for (int i = 0; i < 4; ++i) { f32x4 v = p[i]; s += v[0] + v[1] + v[2] + v[3]; }
    const_cast<float*>(bias0)[row] = 1.f / s;
    return;
  }

  const int lane = tid & 63;
  const int w    = tid >> 6;          // S: 0..15, else 0..7
  const int wr   = w >> 2;            // S: 0..3 (64-row band), else 0..1
  const int wc   = w & 3;             // 0..3 (64-col band)

  // ---- XCD-aware decode (1D grids) ----
  int bm_b, bn_b, z = 0, tt = 0;
  if (MODE == G_QKVW) {        // nwg=768: 8 xcd x {bn0..1 fast, 16 bm, z0..2 slow}
    int xcd = d & 7, sl_ = d >> 3;
    bn_b = sl_ & 1; bm_b = xcd * 16 + ((sl_ >> 1) & 15); z = sl_ >> 5;
  } else if (MODE == G_S) {    // nwg=1024: 8 xcd x {bm0..1 fast (share B), 16 bn, 4 t}
    int xcd = d & 7, sl_ = d >> 3;
    bm_b = xcd * 2 + (sl_ & 1); bn_b = (sl_ >> 1) & 15; tt = sl_ >> 5;
  } else if (MODE == G_PVT) {  // nwg=512: 8 xcd x {bm0..3 fast, bn0..1, z0..1, t0..3}
    int xcd = d & 7, sl_ = d >> 3;
    bm_b = xcd * 4 + (sl_ & 3); bn_b = (sl_ >> 2) & 1; z = (sl_ >> 3) & 1; tt = sl_ >> 4;
  } else {                     // WPV nwg=8 (4 bm x 2 bn)
    bm_b = d & 3; bn_b = d >> 2;
  }
  const int bm0 = bm_b * BM;
  const int bn0 = bn_b * 256;

  const short* Abase = A;
  const short* Bt = B0;
  const float* bias = bias0;
  float scale = 1.f;
  int ktile0 = 0;
  if (MODE == G_QKVW) {
    Bt    = (z == 0) ? B0 : (z == 1) ? B1 : B2;
    bias  = (z == 0) ? bias0 : (z == 1) ? bias1 : bias2;
    scale = (z == 0) ? scale0 : 1.f;
  }
  if (MODE == G_S) {           // per-t slices of Q and K (each 4096x512)
    Abase = A  + (size_t)tt * 2097152;
    Bt    = B0 + (size_t)tt * 2097152;
  }
  if (MODE == G_PVT) {         // A = SP[t] (4096x4096); B col-offset t*4096 in VWT
    Abase  = A  + (size_t)tt * 16777216;
    Bt     = B0 + (size_t)tt * 4096;
    ktile0 = z * NKT;          // split-2 over K=4096 -> 2048 per block
  }

  __shared__ __align__(16) short Ls[LSSZ];

  const int r0 = tid >> 2, s0 = tid & 3;   // S: r0 in [0,256); else [0,128)
  const int srcoff = ((s0 - (r0 >> 1)) & 3) << 3;
  const short* Asrc = Abase + (size_t)(bm0 + r0) * lda + ktile0 * 32 + srcoff;
  const short* Bsrc = Bt    + (size_t)(bn0 + r0) * ldb + ktile0 * 32 + srcoff;
  const size_t offB128 = (size_t)128 * ldb;   // wave-uniform -> SGPR

  auto stage = [&](int kt, int b) {
    short* As = Ls + b * BUFSZ;
    short* Bs = As + AR32;
    int kc = kt * 32;
    if (MODE == G_S) {               // 2 glds: A row r0, B row r0 (r0 covers 256)
      glds16(Asrc + kc, As + tid * 8);
      glds16(Bsrc + kc, Bs + tid * 8);
    } else {                         // 3 glds: A row r0; B rows r0, r0+128
      glds16(Asrc + kc,           As + tid * 8);
      glds16(Bsrc + kc,           Bs + tid * 8);
      glds16(Bsrc + kc + offB128, Bs + 4096 + tid * 8);
    }
  };

  const int lr = lane & 15, sl = lane >> 4;
  int aoff[4], boff[4];
#pragma unroll
  for (int i = 0; i < 4; ++i) {
    int ra = wr * 64 + i * 16 + lr;                 // [0,BM)
    aoff[i] = ra * 32 + (((sl + (ra >> 1)) & 3) << 3);
    int rb = wc * 64 + i * 16 + lr;                 // [0,256)
    boff[i] = AR32 + rb * 32 + (((sl + (rb >> 1)) & 3) << 3);
  }

  f32x4 acc[4][4] = {};

  stage(0, 0);
  stage(1, 1);
  asm volatile("s_waitcnt vmcnt(%0)" :: "i"(NVM) : "memory");  // tile0 landed
  asm volatile("s_barrier" ::: "memory");

  int bcur = 0;
  for (int t = 0; t < NKT; ++t) {
    int b2 = bcur + 2; if (b2 >= 3) b2 -= 3;         // (t+2)%3 — never the read buffer
    if (t + 2 < NKT) stage(t + 2, b2);
    const short* As = Ls + bcur * BUFSZ;
    short8 af[4], bf8[4];
#pragma unroll
    for (int i = 0; i < 4; ++i) af[i] = *(const short8*)&As[aoff[i]];
#pragma unroll
    for (int i = 0; i < 4; ++i) bf8[i] = *(const short8*)&As[boff[i]];
    __builtin_amdgcn_s_setprio(1);
#pragma unroll
    for (int mi = 0; mi < 4; ++mi)
#pragma unroll
      for (int ni = 0; ni < 4; ++ni)
        acc[mi][ni] = __builtin_amdgcn_mfma_f32_16x16x32_bf16(af[mi], bf8[ni], acc[mi][ni], 0, 0, 0);
    __builtin_amdgcn_s_setprio(0);
    // steady: tiles t+1 + t+2 outstanding -> vmcnt(NVM) retires tile t+1
    if (t + 2 < NKT)        { asm volatile("s_waitcnt vmcnt(%0)" :: "i"(NVM) : "memory"); }
    else if (t == NKT - 2)  { asm volatile("s_waitcnt vmcnt(0)" ::: "memory"); }
    asm volatile("s_barrier" ::: "memory");
    bcur = (bcur == 2) ? 0 : bcur + 1;
  }

  if ((MODE == G_PVT) || (MODE == G_QKVW && z == 2)) {
    // transposed epilogue: C^T bounce [256 o][132], all waves, one barrier
#pragma unroll
    for (int ni = 0; ni < 4; ++ni) {
      int brow = wc * 64 + ni * 16 + lr;            // [0,256)
      float badd = (MODE == G_QKVW) ? bias[bn0 + brow] : 0.f;
#pragma unroll
      for (int mi = 0; mi < 4; ++mi) {
        int bcol0 = wr * 64 + mi * 16 + sl * 4;     // [0,128)
        short4v pk;
#pragma unroll
        for (int r = 0; r < 4; ++r) pk[r] = f2bf(acc[mi][ni][r] + badd);
        *(short4v*)&Ls[brow * 132 + bcol0] = pk;
      }
    }
    __syncthreads();
#pragma unroll
    for (int it = 0; it < 8; ++it) {
      int u = it * THREADS + tid;                   // [0,4096)
      int ol = u >> 4, c8 = (u & 15) * 8;           // 256 rows x 128 cols
      short8 v = *(const short8*)&Ls[ol * 132 + c8];
      if (MODE == G_PVT)
        *(short8*)&out0[((size_t)(tt * 2 + z) * 512 + bn0 + ol) * 4096 + bm0 + c8] = v;
      else
        *(short8*)&outT[(size_t)(bn0 + ol) * 16384 + bm0 + c8] = v;
    }
  } else {
    // normal epilogue: C bounce [BM][264], all waves, one barrier
#pragma unroll
    for (int mi = 0; mi < 4; ++mi) {
      int row0 = wr * 64 + mi * 16 + sl * 4;        // [0,BM)
#pragma unroll
      for (int ni = 0; ni < 4; ++ni) {
        int col = wc * 64 + ni * 16 + lr;           // [0,256)
        float badd = (MODE == G_QKVW) ? bias[bn0 + col] : 0.f;
#pragma unroll
        for (int r = 0; r < 4; ++r) {
          float v = acc[mi][ni][r];
          if (MODE == G_QKVW) v = (v + badd) * scale;
          if (MODE == G_S)    v = __expf(v);
          Ls[(row0 + r) * 264 + col] = f2bf(v);
        }
      }
    }
    __syncthreads();
#pragma unroll
    for (int it = 0; it < 8; ++it) {
      int u = it * THREADS + tid;                   // [0, BM*32)
      int rl = u >> 5, c8 = (u & 31) * 8;           // BM rows x 256 cols
      short8 v = *(const short8*)&Ls[rl * 264 + c8];
      int grow = bm0 + rl;
      if (MODE == G_QKVW)
        *(short8*)&out0[(size_t)z * 16384 * 512 + (size_t)grow * 512 + bn0 + c8] = v;
      else if (MODE == G_S)
        *(short8*)&out0[(size_t)tt * 16777216 + (size_t)grow * 4096 + bn0 + c8] = v;
      else
        *(short8*)&out0[(size_t)grow * 512 + bn0 + c8] = v;
      if (MODE == G_S) {
        float s = 0.f;
#pragma unroll
        for (int j = 0; j < 8; ++j) s += bf2f(v[j]);
        s += __shfl_xor(s, 1); s += __shfl_xor(s, 2); s += __shfl_xor(s, 4);
        s += __shfl_xor(s, 8); s += __shfl_xor(s, 16);
        if ((lane & 31) == 0) spart[((size_t)tt * 4096 + grow) * 32 + bn_b] = s;
      }
    }
  }
}

// ---- out[o][t*4096+n] = x + rinv[n] * sum_s PVp[t][s][o][n]  (all t, 2 splits) ----
__global__ __launch_bounds__(256) void reduce_pv(const short* __restrict__ PVp,
                                                 const float* __restrict__ rinv,
                                                 const float* __restrict__ x,
                                                 float* __restrict__ out) {
  int b = blockIdx.x;                          // 8192 blocks
  int t = b >> 11;
  int gid = (b & 2047) * 256 + threadIdx.x;    // [0, 524288)
  int o = gid >> 10, n = (gid & 1023) * 4;
  size_t oi = (size_t)o * 16384 + t * 4096 + n;
  const short* P  = PVp + (size_t)t * 4194304;     // 2*512*4096
  const float* rv = rinv + (size_t)t * 4096;
  float4 xr = *(const float4*)&x[oi];
  float4 rr = *(const float4*)&rv[n];
  float s0 = 0.f, s1 = 0.f, s2 = 0.f, s3 = 0.f;
#pragma unroll
  for (int sp = 0; sp < 2; ++sp) {
    short4v v = *(const short4v*)&P[((size_t)sp * 512 + o) * 4096 + n];
    s0 += bf2f(v.x); s1 += bf2f(v.y); s2 += bf2f(v.z); s3 += bf2f(v.w);
  }
  float4 og;
  og.x = xr.x + s0 * rr.x;
  og.y = xr.y + s1 * rr.y;
  og.z = xr.z + s2 * rr.z;
  og.w = xr.w + s3 * rr.w;
  *(float4*)&out[oi] = og;
}

extern "C" void kernel_launch(void* const* d_in, const int* in_sizes, int n_in,
                              void* d_out, int out_size, void* d_ws, size_t ws_size,
                              hipStream_t stream) {
  const float* x     = (const float*)d_in[0];
  const float* gamma = (const float*)d_in[1];
  const float* beta  = (const float*)d_in[2];
  const float* wq    = (const float*)d_in[3];
  const float* bq    = (const float*)d_in[4];
  const float* wk    = (const float*)d_in[5];
  const float* bk    = (const float*)d_in[6];
  const float* wv    = (const float*)d_in[7];
  const float* bv    = (const float*)d_in[8];
  const float* wp    = (const float*)d_in[9];
  const float* bp    = (const float*)d_in[10];

  char* ws = (char*)d_ws;
  size_t off = 0;
  auto alloc = [&](size_t bytes) -> void* {
    void* p = ws + off;
    off += (bytes + 255) & ~(size_t)255;
    return p;
  };
  // SP_all first; HnT aliases its head (HnT dead before S_all writes SP).
  short* SP   = (short*)alloc((size_t)4 * 4096 * 4096 * 2);   // 128 MiB
  short* HnT  = SP;                                           // alias, 16 MiB
  short* QK   = (short*)alloc((size_t)2 * 16384 * 512 * 2);   // 32 MiB
  short* VWT  = (short*)alloc((size_t)512 * 16384 * 2);       // 16 MiB
  short* PVp  = (short*)alloc((size_t)4 * 2 * 512 * 4096 * 2);// 32 MiB
  short* WqB  = (short*)alloc((size_t)512 * 512 * 2);
  short* WkB  = (short*)alloc((size_t)512 * 512 * 2);
  short* WvB  = (short*)alloc((size_t)512 * 512 * 2);
  short* WpB  = (short*)alloc((size_t)512 * 512 * 2);
  short* WvT  = (short*)alloc((size_t)512 * 512 * 2);
  short* WpvB = (short*)alloc((size_t)512 * 512 * 2);
  float* spart= (float*)alloc((size_t)16384 * 32 * 4);        // 2 MiB
  float* rinv = (float*)alloc((size_t)16384 * 4);
  float* bpv  = (float*)alloc((size_t)512 * 4);
  float* part = (float*)alloc(32 * 8 * 2 * 4);
  float* stats= (float*)alloc(64 * 4);
  if (off > ws_size) return;

  const float scale = 0.044194173824159216f;  // 512^-0.5

  // A: weight cvt U gn stats pass 1
  pre_a<<<1280, 256, 0, stream>>>(wq, WqB, wk, WkB, wv, WvB, wp, WpB, x, part);
  // B: Wv transpose U gn stats pass 2 U bpv
  pre_b<<<67, 256, 0, stream>>>(WvB, WvT, part, stats, wp, bv, bpv);
  // C: Wpv = Wp @ Wv (blocks 0..7) U gn_apply -> HnT (blocks 8..2055)
  gemm256<G_WPV, 16><<<2056, 512, 0, stream>>>(
      WpB, WvT, (const short*)x, nullptr, WpvB, HnT, stats, gamma, beta, nullptr, 1.f, 512, 512);

  // z=0: Q (scaled, bias bq) -> QK[0]; z=1: K (bias bk) -> QK[1];
  // z=2: VW = Wpv.hn + bpv  -> VWT[o][tn] (transposed epilogue)
  gemm256<G_QKVW, 16><<<768, 512, 0, stream>>>(
      HnT, WqB, WkB, WpvB, QK, VWT, bq, bk, bpv, nullptr, scale, 512, 512);

  // SP[t] = exp(Q[t].K[t]^T) + per-block row sums; 256x256 tiles, 1024 thr
  gemm256<G_S, 16><<<1024, 1024, 0, stream>>>(
      QK, QK + (size_t)16384 * 512, nullptr, nullptr, SP, nullptr, nullptr, nullptr, nullptr, spart,
      1.f, 512, 512);
  // PVp split-2, all t (blocks 0..511) U rowsum -> rinv (blocks 512..543)
  gemm256<G_PVT, 64><<<544, 512, 0, stream>>>(
      SP, VWT, nullptr, nullptr, PVp, nullptr, rinv, nullptr, nullptr, spart, 1.f, 4096, 16384);
  reduce_pv<<<8192, 256, 0, stream>>>(PVp, rinv, x, (float*)d_out);
}

// Round 20
// 247.977 us; speedup vs baseline: 1.0734x; 1.0734x over previous
//
#include <hip/hip_runtime.h>
#include <hip/hip_bf16.h>

typedef __attribute__((ext_vector_type(8))) short short8;
typedef __attribute__((ext_vector_type(4))) short short4v;
typedef __attribute__((ext_vector_type(4))) float f32x4;

__device__ __forceinline__ short f2bf(float f) {
  __hip_bfloat16 h = __float2bfloat16(f);
  return *reinterpret_cast<short*>(&h);
}
__device__ __forceinline__ float bf2f(short s) {
  return __uint_as_float(((unsigned)(unsigned short)s) << 16);
}
__device__ __forceinline__ void glds16(const short* src, short* dst) {
  __builtin_amdgcn_global_load_lds(
      (const __attribute__((address_space(1))) unsigned int*)src,
      (__attribute__((address_space(3))) unsigned int*)dst, 16, 0, 0);
}
__device__ __forceinline__ float wave_red_sum(float v) {
  for (int i = 1; i < 64; i <<= 1) v += __shfl_xor(v, i);
  return v;
}

// ---- merged pre-phase A: cvt_w4 (blocks 0..1023) U gn_stats1 (1024..1279) ----
__global__ __launch_bounds__(256) void pre_a(const float* __restrict__ w0, short* __restrict__ o0,
                                             const float* __restrict__ w1, short* __restrict__ o1,
                                             const float* __restrict__ w2, short* __restrict__ o2,
                                             const float* __restrict__ w3, short* __restrict__ o3,
                                             const float* __restrict__ x, float* __restrict__ part) {
  int b = blockIdx.x;
  if (b < 1024) {
    int which = b >> 8;
    const float* w = (which == 0) ? w0 : (which == 1) ? w1 : (which == 2) ? w2 : w3;
    short* o       = (which == 0) ? o0 : (which == 1) ? o1 : (which == 2) ? o2 : o3;
    int i = (b & 255) * 256 + threadIdx.x;
    float4 v = ((const float4*)w)[i];
    short4v r;
    r.x = f2bf(v.x); r.y = f2bf(v.y); r.z = f2bf(v.z); r.w = f2bf(v.w);
    *(short4v*)&o[i*4] = r;
    return;
  }
  int u = b - 1024;
  int g = u & 31, s = u >> 5;
  const float4* base = (const float4*)(x + (size_t)g * 262144 + (size_t)s * 32768);
  float sum = 0.f, sq = 0.f;
  for (int i = threadIdx.x; i < 8192; i += 256) {
    float4 v = base[i];
    sum += v.x + v.y + v.z + v.w;
    sq  += v.x*v.x + v.y*v.y + v.z*v.z + v.w*v.w;
  }
  sum = wave_red_sum(sum); sq = wave_red_sum(sq);
  __shared__ float ls[4], lq[4];
  int w = threadIdx.x >> 6, lane = threadIdx.x & 63;
  if (lane == 0) { ls[w] = sum; lq[w] = sq; }
  __syncthreads();
  if (threadIdx.x == 0) {
    part[(g*8 + s)*2 + 0] = ls[0]+ls[1]+ls[2]+ls[3];
    part[(g*8 + s)*2 + 1] = lq[0]+lq[1]+lq[2]+lq[3];
  }
}

// ---- merged pre-phase B: t512 (0..63) U gn_stats2 (64) U bpv_k (65..66) ----
__global__ __launch_bounds__(256) void pre_b(const short* __restrict__ in, short* __restrict__ out,
                                             const float* __restrict__ part, float* __restrict__ stats,
                                             const float* __restrict__ wp, const float* __restrict__ bv,
                                             float* __restrict__ bpv) {
  __shared__ short T[64 * 72];
  int b = blockIdx.x;
  int tid = threadIdx.x;
  if (b < 64) {
    int c0 = (b & 7) * 64, i0 = (b >> 3) * 64;
#pragma unroll
    for (int it = 0; it < 2; ++it) {
      int u = it * 256 + tid;
      int r = u >> 3, k8 = (u & 7) * 8;
      *(short8*)&T[r * 72 + k8] = *(const short8*)&in[(size_t)(c0 + r) * 512 + i0 + k8];
    }
    __syncthreads();
#pragma unroll
    for (int it = 0; it < 2; ++it) {
      int u = it * 256 + tid;
      int c = u & 63, tg = u >> 6;
      short8 o;
#pragma unroll
      for (int j = 0; j < 8; ++j) o[j] = T[(tg * 8 + j) * 72 + c];
      *(short8*)&out[(size_t)(i0 + c) * 512 + c0 + tg * 8] = o;
    }
    return;
  }
  if (b == 64) {
    int g = tid;
    if (g < 32) {
      float s1 = 0.f, s2 = 0.f;
      for (int s = 0; s < 8; ++s) { s1 += part[(g*8+s)*2]; s2 += part[(g*8+s)*2+1]; }
      float mean = s1 * (1.f/262144.f);
      float var  = s2 * (1.f/262144.f) - mean*mean;
      stats[g]      = mean;
      stats[32 + g] = rsqrtf(var + 1e-6f);
    }
    return;
  }
  int o = (b - 65) * 256 + tid;
  float s = 0.f;
  for (int c = 0; c < 512; ++c) s += wp[(size_t)o * 512 + c] * bv[c];
  bpv[o] = s;
}

// ---- 128x256-tile GEMM, 8 waves (2x4), per-wave 64x64, BK=32 ----
// 3-buffer, single barrier per k-step, compiler-scheduled (R12 core).
// Fused riders: G_WPV blocks >=8 run gn_apply (x via B1, stats/gamma/beta via
// bias0..2, HnT via outT); G_PVT blocks >=512 run rowsum (rinv via bias0).
enum { G_QKVW = 0, G_S = 1, G_PVT = 2, G_WPV = 3 };

template<int MODE, int NKT>
__global__ __launch_bounds__(512, 4) void gemm256(
    const short* __restrict__ A, const short* __restrict__ B0,
    const short* __restrict__ B1, const short* __restrict__ B2,
    short* __restrict__ out0, short* __restrict__ outT,
    const float* __restrict__ bias0, const float* __restrict__ bias1, const float* __restrict__ bias2,
    float* __restrict__ spart, float scale0,
    int lda, int ldb) {
  const int tid  = threadIdx.x;
  const int d    = blockIdx.x;

  if (MODE == G_WPV && d >= 8) {
    // ---- gn_apply rider (2048 blocks, 512 thr; bit-identical math) ----
    int u = d - 8;
    int n  = (u & 7) * 512 + tid;
    int c0 = ((u >> 3) & 63) * 8;
    int t  = u >> 9;
    const float* xx = (const float*)B1;
    short8 o8;
#pragma unroll
    for (int j = 0; j < 8; ++j) {
      int c = c0 + j, g = c >> 4;
      float v  = xx[(size_t)c * 16384 + t * 4096 + n];
      float hv = (v - bias0[g]) * bias0[32 + g] * bias1[c] + bias2[c];
      o8[j] = f2bf(hv);
    }
    *(short8*)&outT[((size_t)t * 4096 + n) * 512 + c0] = o8;
    return;
  }
  if (MODE == G_PVT && d >= 512) {
    // ---- rowsum rider (32 blocks, 512 thr; rowsum_k's exact order) ----
    int row = (d - 512) * 512 + tid;
    const f32x4* p = (const f32x4*)(spart + (size_t)row * 32);
    float s = 0.f;
#pragma unroll
    for (int i = 0; i < 4; ++i) { f32x4 v = p[i]; s += v[0] + v[1] + v[2] + v[3]; }
    const_cast<float*>(bias0)[row] = 1.f / s;
    return;
  }

  const int lane = tid & 63;
  const int w    = tid >> 6;          // 0..7
  const int wr   = w >> 2;            // 0..1 (M half, 64 rows)
  const int wc   = w & 3;             // 0..3 (N quarter, 64 cols)

  // ---- XCD-aware decode (1D grids, nwg % 8 == 0 except WPV) ----
  int bm_b, bn_b, z = 0, tt = 0;
  if (MODE == G_QKVW) {        // nwg=768: 8 xcd x {bn0..1 fast, 16 bm, z0..2 slow}
    int xcd = d & 7, sl_ = d >> 3;
    bn_b = sl_ & 1; bm_b = xcd * 16 + ((sl_ >> 1) & 15); z = sl_ >> 5;
  } else if (MODE == G_S) {    // nwg=2048: 8 xcd x {bm0..3 fast (share B), 16 bn, 4 t}
    int xcd = d & 7, sl_ = d >> 3;
    bm_b = xcd * 4 + (sl_ & 3); bn_b = (sl_ >> 2) & 15; tt = sl_ >> 6;
  } else if (MODE == G_PVT) {  // nwg=512: 8 xcd x {bm0..3 fast, bn0..1, z0..1, t0..3}
    int xcd = d & 7, sl_ = d >> 3;
    bm_b = xcd * 4 + (sl_ & 3); bn_b = (sl_ >> 2) & 1; z = (sl_ >> 3) & 1; tt = sl_ >> 4;
  } else {                     // WPV nwg=8 (4 bm x 2 bn)
    bm_b = d & 3; bn_b = d >> 2;
  }
  const int bm0 = bm_b * 128;
  const int bn0 = bn_b * 256;

  const short* Abase = A;
  const short* Bt = B0;
  const float* bias = bias0;
  float scale = 1.f;
  int ktile0 = 0;
  if (MODE == G_QKVW) {
    Bt    = (z == 0) ? B0 : (z == 1) ? B1 : B2;
    bias  = (z == 0) ? bias0 : (z == 1) ? bias1 : bias2;
    scale = (z == 0) ? scale0 : 1.f;
  }
  if (MODE == G_S) {           // per-t slices of Q and K (each 4096x512)
    Abase = A  + (size_t)tt * 2097152;
    Bt    = B0 + (size_t)tt * 2097152;
  }
  if (MODE == G_PVT) {         // A = SP[t] (4096x4096); B col-offset t*4096 in VWT
    Abase  = A  + (size_t)tt * 16777216;
    Bt     = B0 + (size_t)tt * 4096;
    ktile0 = z * NKT;          // split-2 over K=4096 -> 2048 per block
  }

  // staging: 3 bufs x (A 128x32 + B 256x32) = 3x12288 shorts = 72KB.
  // epilogue bounce (33792 shorts) overlays the same space. 2 blocks/CU.
  __shared__ __align__(16) short Ls[36864];

  const int r0 = tid >> 2, s0 = tid & 3;   // r0 in [0,128)
  const int srcoff = ((s0 - (r0 >> 1)) & 3) << 3;
  const short* Asrc = Abase + (size_t)(bm0 + r0) * lda + ktile0 * 32 + srcoff;
  const short* Bsrc = Bt    + (size_t)(bn0 + r0) * ldb + ktile0 * 32 + srcoff;
  const size_t offB128 = (size_t)128 * ldb;   // wave-uniform -> SGPR

  auto stage = [&](int kt, int b) {   // 3 glds/thread: A rows r0; B rows r0, r0+128
    short* As = Ls + b * 12288;
    short* Bs = As + 4096;
    int kc = kt * 32;
    glds16(Asrc + kc,           As + tid * 8);
    glds16(Bsrc + kc,           Bs + tid * 8);
    glds16(Bsrc + kc + offB128, Bs + 4096 + tid * 8);
  };

  const int lr = lane & 15, sl = lane >> 4;
  int aoff[4], boff[4];
#pragma unroll
  for (int i = 0; i < 4; ++i) {
    int ra = wr * 64 + i * 16 + lr;                 // [0,128)
    aoff[i] = ra * 32 + (((sl + (ra >> 1)) & 3) << 3);
    int rb = wc * 64 + i * 16 + lr;                 // [0,256)
    boff[i] = 4096 + rb * 32 + (((sl + (rb >> 1)) & 3) << 3);
  }

  f32x4 acc[4][4] = {};

  stage(0, 0);
  stage(1, 1);
  asm volatile("s_waitcnt vmcnt(3)" ::: "memory");   // tile0 landed (tile1 in flight)
  asm volatile("s_barrier" ::: "memory");

  int bcur = 0;
  for (int t = 0; t < NKT; ++t) {
    int b2 = bcur + 2; if (b2 >= 3) b2 -= 3;         // (t+2)%3 — never the read buffer
    if (t + 2 < NKT) stage(t + 2, b2);
    const short* As = Ls + bcur * 12288;
    short8 af[4], bf8[4];
#pragma unroll
    for (int i = 0; i < 4; ++i) af[i] = *(const short8*)&As[aoff[i]];
#pragma unroll
    for (int i = 0; i < 4; ++i) bf8[i] = *(const short8*)&As[boff[i]];
    __builtin_amdgcn_s_setprio(1);
#pragma unroll
    for (int mi = 0; mi < 4; ++mi)
#pragma unroll
      for (int ni = 0; ni < 4; ++ni)
        acc[mi][ni] = __builtin_amdgcn_mfma_f32_16x16x32_bf16(af[mi], bf8[ni], acc[mi][ni], 0, 0, 0);
    __builtin_amdgcn_s_setprio(0);
    // steady: tiles t+1 (3) + t+2 (3) outstanding -> vmcnt(3) retires tile t+1
    if (t + 2 < NKT)        { asm volatile("s_waitcnt vmcnt(3)" ::: "memory"); }
    else if (t == NKT - 2)  { asm volatile("s_waitcnt vmcnt(0)" ::: "memory"); }
    asm volatile("s_barrier" ::: "memory");
    bcur = (bcur == 2) ? 0 : bcur + 1;
  }

  if ((MODE == G_PVT) || (MODE == G_QKVW && z == 2)) {
    // transposed epilogue: C^T bounce [256 o][132], all waves, one barrier
#pragma unroll
    for (int ni = 0; ni < 4; ++ni) {
      int brow = wc * 64 + ni * 16 + lr;            // [0,256)
      float badd = (MODE == G_QKVW) ? bias[bn0 + brow] : 0.f;
#pragma unroll
      for (int mi = 0; mi < 4; ++mi) {
        int bcol0 = wr * 64 + mi * 16 + sl * 4;     // [0,128)
        short4v pk;
#pragma unroll
        for (int r = 0; r < 4; ++r) pk[r] = f2bf(acc[mi][ni][r] + badd);
        *(short4v*)&Ls[brow * 132 + bcol0] = pk;
      }
    }
    __syncthreads();
#pragma unroll
    for (int it = 0; it < 8; ++it) {
      int u = it * 512 + tid;                       // [0,4096)
      int ol = u >> 4, c8 = (u & 15) * 8;           // 256 rows x 128 cols
      short8 v = *(const short8*)&Ls[ol * 132 + c8];
      if (MODE == G_PVT)
        *(short8*)&out0[((size_t)(tt * 2 + z) * 512 + bn0 + ol) * 4096 + bm0 + c8] = v;
      else
        *(short8*)&outT[(size_t)(bn0 + ol) * 16384 + bm0 + c8] = v;
    }
  } else {
    // normal epilogue: C bounce [128][264], all waves, one barrier
#pragma unroll
    for (int mi = 0; mi < 4; ++mi) {
      int row0 = wr * 64 + mi * 16 + sl * 4;        // [0,128)
#pragma unroll
      for (int ni = 0; ni < 4; ++ni) {
        int col = wc * 64 + ni * 16 + lr;           // [0,256)
        float badd = (MODE == G_QKVW) ? bias[bn0 + col] : 0.f;
#pragma unroll
        for (int r = 0; r < 4; ++r) {
          float v = acc[mi][ni][r];
          if (MODE == G_QKVW) v = (v + badd) * scale;
          if (MODE == G_S)    v = __expf(v);
          Ls[(row0 + r) * 264 + col] = f2bf(v);
        }
      }
    }
    __syncthreads();
#pragma unroll
    for (int it = 0; it < 8; ++it) {
      int u = it * 512 + tid;                       // [0,4096)
      int rl = u >> 5, c8 = (u & 31) * 8;           // 128 rows x 256 cols
      short8 v = *(const short8*)&Ls[rl * 264 + c8];
      int grow = bm0 + rl;
      if (MODE == G_QKVW)
        *(short8*)&out0[(size_t)z * 16384 * 512 + (size_t)grow * 512 + bn0 + c8] = v;
      else if (MODE == G_S)
        *(short8*)&out0[(size_t)tt * 16777216 + (size_t)grow * 4096 + bn0 + c8] = v;
      else
        *(short8*)&out0[(size_t)grow * 512 + bn0 + c8] = v;
      if (MODE == G_S) {
        float s = 0.f;
#pragma unroll
        for (int j = 0; j < 8; ++j) s += bf2f(v[j]);
        s += __shfl_xor(s, 1); s += __shfl_xor(s, 2); s += __shfl_xor(s, 4);
        s += __shfl_xor(s, 8); s += __shfl_xor(s, 16);
        if ((lane & 31) == 0) spart[((size_t)tt * 4096 + grow) * 32 + bn_b] = s;
      }
    }
  }
}

// ---- out[o][t*4096+n] = x + rinv[n] * sum_s PVp[t][s][o][n]  (all t, 2 splits) ----
__global__ __launch_bounds__(256) void reduce_pv(const short* __restrict__ PVp,
                                                 const float* __restrict__ rinv,
                                                 const float* __restrict__ x,
                                                 float* __restrict__ out) {
  int b = blockIdx.x;                          // 8192 blocks
  int t = b >> 11;
  int gid = (b & 2047) * 256 + threadIdx.x;    // [0, 524288)
  int o = gid >> 10, n = (gid & 1023) * 4;
  size_t oi = (size_t)o * 16384 + t * 4096 + n;
  const short* P  = PVp + (size_t)t * 4194304;     // 2*512*4096
  const float* rv = rinv + (size_t)t * 4096;
  float4 xr = *(const float4*)&x[oi];
  float4 rr = *(const float4*)&rv[n];
  float s0 = 0.f, s1 = 0.f, s2 = 0.f, s3 = 0.f;
#pragma unroll
  for (int sp = 0; sp < 2; ++sp) {
    short4v v = *(const short4v*)&P[((size_t)sp * 512 + o) * 4096 + n];
    s0 += bf2f(v.x); s1 += bf2f(v.y); s2 += bf2f(v.z); s3 += bf2f(v.w);
  }
  float4 og;
  og.x = xr.x + s0 * rr.x;
  og.y = xr.y + s1 * rr.y;
  og.z = xr.z + s2 * rr.z;
  og.w = xr.w + s3 * rr.w;
  *(float4*)&out[oi] = og;
}

extern "C" void kernel_launch(void* const* d_in, const int* in_sizes, int n_in,
                              void* d_out, int out_size, void* d_ws, size_t ws_size,
                              hipStream_t stream) {
  const float* x     = (const float*)d_in[0];
  const float* gamma = (const float*)d_in[1];
  const float* beta  = (const float*)d_in[2];
  const float* wq    = (const float*)d_in[3];
  const float* bq    = (const float*)d_in[4];
  const float* wk    = (const float*)d_in[5];
  const float* bk    = (const float*)d_in[6];
  const float* wv    = (const float*)d_in[7];
  const float* bv    = (const float*)d_in[8];
  const float* wp    = (const float*)d_in[9];
  const float* bp    = (const float*)d_in[10];

  char* ws = (char*)d_ws;
  size_t off = 0;
  auto alloc = [&](size_t bytes) -> void* {
    void* p = ws + off;
    off += (bytes + 255) & ~(size_t)255;
    return p;
  };
  // SP_all first; HnT aliases its head (HnT dead before S_all writes SP).
  short* SP   = (short*)alloc((size_t)4 * 4096 * 4096 * 2);   // 128 MiB
  short* HnT  = SP;                                           // alias, 16 MiB
  short* QK   = (short*)alloc((size_t)2 * 16384 * 512 * 2);   // 32 MiB
  short* VWT  = (short*)alloc((size_t)512 * 16384 * 2);       // 16 MiB
  short* PVp  = (short*)alloc((size_t)4 * 2 * 512 * 4096 * 2);// 32 MiB
  short* WqB  = (short*)alloc((size_t)512 * 512 * 2);
  short* WkB  = (short*)alloc((size_t)512 * 512 * 2);
  short* WvB  = (short*)alloc((size_t)512 * 512 * 2);
  short* WpB  = (short*)alloc((size_t)512 * 512 * 2);
  short* WvT  = (short*)alloc((size_t)512 * 512 * 2);
  short* WpvB = (short*)alloc((size_t)512 * 512 * 2);
  float* spart= (float*)alloc((size_t)16384 * 32 * 4);        // 2 MiB
  float* rinv = (float*)alloc((size_t)16384 * 4);
  float* bpv  = (float*)alloc((size_t)512 * 4);
  float* part = (float*)alloc(32 * 8 * 2 * 4);
  float* stats= (float*)alloc(64 * 4);
  if (off > ws_size) return;

  const float scale = 0.044194173824159216f;  // 512^-0.5

  // A: weight cvt U gn stats pass 1
  pre_a<<<1280, 256, 0, stream>>>(wq, WqB, wk, WkB, wv, WvB, wp, WpB, x, part);
  // B: Wv transpose U gn stats pass 2 U bpv
  pre_b<<<67, 256, 0, stream>>>(WvB, WvT, part, stats, wp, bv, bpv);
  // C: Wpv = Wp @ Wv (blocks 0..7) U gn_apply -> HnT (blocks 8..2055)
  gemm256<G_WPV, 16><<<2056, 512, 0, stream>>>(
      WpB, WvT, (const short*)x, nullptr, WpvB, HnT, stats, gamma, beta, nullptr, 1.f, 512, 512);

  // z=0: Q (scaled, bias bq) -> QK[0]; z=1: K (bias bk) -> QK[1];
  // z=2: VW = Wpv.hn + bpv  -> VWT[o][tn] (transposed epilogue)
  gemm256<G_QKVW, 16><<<768, 512, 0, stream>>>(
      HnT, WqB, WkB, WpvB, QK, VWT, bq, bk, bpv, nullptr, scale, 512, 512);

  // SP[t] = exp(Q[t].K[t]^T) + per-block row sums, all t in one launch
  gemm256<G_S, 16><<<2048, 512, 0, stream>>>(
      QK, QK + (size_t)16384 * 512, nullptr, nullptr, SP, nullptr, nullptr, nullptr, nullptr, spart,
      1.f, 512, 512);
  // PVp split-2, all t (blocks 0..511) U rowsum -> rinv (blocks 512..543)
  gemm256<G_PVT, 64><<<544, 512, 0, stream>>>(
      SP, VWT, nullptr, nullptr, PVp, nullptr, rinv, nullptr, nullptr, spart, 1.f, 4096, 16384);
  reduce_pv<<<8192, 256, 0, stream>>>(PVp, rinv, x, (float*)d_out);
}